// Round 5
// baseline (107.750 us; speedup 1.0000x reference)
//
#include <hip/hip_runtime.h>
#include <cstdint>
#include <cstddef>

// ---------------------------------------------------------------------------
// Multi-scale region distillation loss — single pass, per-wave async
// streaming pipeline (global_load_lds + counted vmcnt), fused class bins.
//
// Per pixel (NCHW channel reduction):
//   Zn = sum_c exp(xn_c), Zo = sum_c exp(xo_c), S = sum_c exp(xn_c)*(xn_c-xo_c)
//   kl = S/Zn - log(Zn) + log(Zo)
// Then per-class mean per scale, coef-weighted, scale weights 1..4.
//
// Input order (verified R3): d_in = {labels, fn0, fo0, fn1, fo1, ...} —
// resolved defensively from in_sizes.
//
// k1 geometry: wave = 64 pixels x WCH channels. Chunk = 8 ch x 64 px x 4B
// = 2KB/tensor (2x global_load_lds w16 each). Double-buffered, 2 chunks in
// flight per wave, no barriers in K-loop. LDS 32KB/block (5 blocks/CU).
// ---------------------------------------------------------------------------

#define TPB 256
#define P3 2048
#define WS_ZERO_FLOATS (P3 * 3 + 256)

#define GLL16(gp, lp) __builtin_amdgcn_global_load_lds(                        \
    (const __attribute__((address_space(1))) unsigned int*)(gp),               \
    (__attribute__((address_space(3))) unsigned int*)(lp), 16, 0, 0)

__global__ __launch_bounds__(TPB)
void k0_zero(float* __restrict__ ws) {
    const int i = blockIdx.x * TPB + threadIdx.x;
    if (i < WS_ZERO_FLOATS) ws[i] = 0.f;
}

// C channels, HW pixels/img, W width, F label stride, NPGRP pixel-groups of
// 64 per block (waves split pixels), WCH channels per wave, SPLIT ch-splits
// across blocks (partials -> global pZ*).
template<int C, int HW, int W, int F, int NPGRP, int WCH, int SPLIT>
__device__ __forceinline__ void scale_pass(const float* __restrict__ fn,
                                           const float* __restrict__ fo,
                                           const int* __restrict__ labels,
                                           int ncls, int sc,
                                           float* __restrict__ pZn,
                                           float* __restrict__ pZo,
                                           float* __restrict__ pS,
                                           float* __restrict__ clsSum,
                                           float* __restrict__ clsCnt,
                                           float* smem, int lb) {
    constexpr int NPIX = NPGRP * 64;        // pixels per block
    constexpr int NPB  = (8 * HW) / NPIX;   // pixel-blocks per scale
    constexpr int NCK  = WCH / 8;           // chunks per wave
    constexpr int NCHG = 4 / NPGRP;         // waves sharing a pixel-group

    const int tid  = threadIdx.x;
    const int wid  = tid >> 6;
    const int lane = tid & 63;
    const int pb = lb % NPB;
    const int sp = lb / NPB;

    const int pg = wid % NPGRP;             // pixel-group of this wave
    const int cg = wid / NPGRP;             // channel-group of this wave

    const int blkpix0 = pb * NPIX;          // first pixel of block (in scale)
    const int p0 = blkpix0 + pg * 64;       // first pixel of wave
    const int b  = p0 / HW;                 // image (64|HW, NPIX|HW)
    const int ppix = p0 % HW;
    const int ch0w = sp * (NCHG * WCH) + cg * WCH;

    const int cst = lane >> 4;              // ch sub-index 0..3 (stage+consume)
    const int qq  = lane & 15;              // pixel-quad 0..15

    // per-lane global base (floats), chunk-ch offset added per STAGE
    const float* gn = fn + ((size_t)b * C + ch0w + cst) * HW + ppix + qq * 4;
    const float* go = fo + ((size_t)b * C + ch0w + cst) * HW + ppix + qq * 4;

    float* wbuf = smem + wid * 2048;        // 8KB staging per wave (2 bufs)

    float zn0=0.f,zn1=0.f,zn2=0.f,zn3=0.f;
    float zo0=0.f,zo1=0.f,zo2=0.f,zo3=0.f;
    float sA0=0.f,sA1=0.f,sA2=0.f,sA3=0.f;

    // LDS layout per buffer d: new[8ch][16q][4] at d*1024, old at +512 floats.
    // GLL writes lane l at base+l*16B = (cst*64 + qq*4) floats -> row ch'=j*4+cst.
#define STAGE(k_, d_) do {                                                     \
        const size_t co_ = (size_t)((k_) * 8) * HW;                            \
        float* lb0_ = wbuf + (d_) * 1024;                                      \
        GLL16(gn + co_,              lb0_);                                    \
        GLL16(gn + co_ + 4 * (size_t)HW, lb0_ + 256);                          \
        GLL16(go + co_,              lb0_ + 512);                              \
        GLL16(go + co_ + 4 * (size_t)HW, lb0_ + 768);                          \
    } while (0)

#define ACC(nv, ov, i_) { const float en_=__expf(nv), eo_=__expf(ov);          \
        zn##i_ += en_; zo##i_ += eo_; sA##i_ += en_ * ((nv) - (ov)); }

    // lane consumes ch rows {2*cst, 2*cst+1} for its quad qq
#define CONSUME(d_) do {                                                       \
        const float* nb_ = wbuf + (d_) * 1024;                                 \
        const float* ob_ = nb_ + 512;                                          \
        const float4 n0_ = *(const float4*)(nb_ + (2*cst  )*64 + qq*4);        \
        const float4 n1_ = *(const float4*)(nb_ + (2*cst+1)*64 + qq*4);        \
        const float4 o0_ = *(const float4*)(ob_ + (2*cst  )*64 + qq*4);        \
        const float4 o1_ = *(const float4*)(ob_ + (2*cst+1)*64 + qq*4);        \
        ACC(n0_.x,o0_.x,0) ACC(n0_.y,o0_.y,1) ACC(n0_.z,o0_.z,2) ACC(n0_.w,o0_.w,3) \
        ACC(n1_.x,o1_.x,0) ACC(n1_.y,o1_.y,1) ACC(n1_.z,o1_.z,2) ACC(n1_.w,o1_.w,3) \
    } while (0)

    STAGE(0, 0);
    STAGE(1, 1);
    for (int k = 0; k < NCK - 1; ++k) {
        asm volatile("s_waitcnt vmcnt(4)" ::: "memory");   // chunk k landed
        __builtin_amdgcn_sched_barrier(0);
        CONSUME(k & 1);
        asm volatile("s_waitcnt lgkmcnt(0)" ::: "memory"); // reads done before overwrite
        __builtin_amdgcn_sched_barrier(0);
        if (k + 2 < NCK) STAGE(k + 2, k & 1);
    }
    asm volatile("s_waitcnt vmcnt(0)" ::: "memory");       // last chunk landed
    __builtin_amdgcn_sched_barrier(0);
    CONSUME((NCK - 1) & 1);

#undef STAGE
#undef ACC
#undef CONSUME

    // ---- block reduce: overlay red[] onto dead staging LDS ----
    __syncthreads();                        // all waves done streaming
    float* red = smem;                      // 256 threads x 12 floats = 12KB
    float* r = red + tid * 12;
    r[0]=zn0; r[1]=zn1; r[2]=zn2;  r[3]=zn3;
    r[4]=zo0; r[5]=zo1; r[6]=zo2;  r[7]=zo3;
    r[8]=sA0; r[9]=sA1; r[10]=sA2; r[11]=sA3;
    float* ls = smem + 3072;
    float* lc = smem + 3104;
    if (tid < 32) { ls[tid] = 0.f; lc[tid] = 0.f; }
    __syncthreads();

    for (int i = tid; i < NPIX; i += TPB) {
        const int Q = i >> 2, j = i & 3;
        const int pgq = (NPGRP == 2) ? (Q >> 4) : 0;
        const int ql = Q & 15;
        float zn = 0.f, zo = 0.f, s = 0.f;
        #pragma unroll
        for (int cgi = 0; cgi < NCHG; ++cgi) {
            #pragma unroll
            for (int g = 0; g < 4; ++g) {
                const float* rr = red + ((pgq + cgi * NPGRP) * 64 + g * 16 + ql) * 12;
                zn += rr[j]; zo += rr[4 + j]; s += rr[8 + j];
            }
        }
        const int qg = blkpix0 + i;         // pixel index within scale
        if (SPLIT == 1) {
            const float kl = s / zn - logf(zn) + logf(zo);
            const int pp = qg % HW;
            const int h = pp / W, w = pp % W;
            const int lab = labels[b * 262144 + (h * F) * 512 + (w * F)];
            if ((unsigned)lab < (unsigned)ncls) {
                atomicAdd(&ls[lab], kl);
                atomicAdd(&lc[lab], 1.0f);
            }
        } else {
            atomicAdd(&pZn[qg], zn);
            atomicAdd(&pZo[qg], zo);
            atomicAdd(&pS[qg],  s);
        }
    }

    if (SPLIT == 1) {
        __syncthreads();
        if (tid < 32) {
            const float cv = lc[tid];
            if (cv != 0.f) {
                atomicAdd(&clsSum[sc * 32 + tid], ls[tid]);
                atomicAdd(&clsCnt[sc * 32 + tid], cv);
            }
        }
    }
}

// Grid: 1728 blocks. Heavy (512KB) s2/s3 blocks first for backfill:
//   [0,128):    s2 64px x 1024ch, SPLIT=1
//   [128,192):  s3 64px x 1024ch, SPLIT=2 (global partials)
//   [192,704):  s1 64px x 512ch
//   [704,1728): s0 128px x 256ch
__global__ __launch_bounds__(TPB, 4)
void k1_fused(const float* __restrict__ fn0, const float* __restrict__ fo0,
              const float* __restrict__ fn1, const float* __restrict__ fo1,
              const float* __restrict__ fn2, const float* __restrict__ fo2,
              const float* __restrict__ fn3, const float* __restrict__ fo3,
              const int* __restrict__ labels, const int* __restrict__ pNC,
              float* __restrict__ pZn, float* __restrict__ pZo,
              float* __restrict__ pS,
              float* __restrict__ clsSum, float* __restrict__ clsCnt) {
    __shared__ float smem[8192];            // 32KB: 4 waves x 8KB staging
    const int ncls = *pNC;
    const int bb = blockIdx.x;
    if (bb < 128) {
        scale_pass<1024, 1024, 32, 16, 1, 256, 1>(fn2, fo2, labels, ncls, 2,
            pZn, pZo, pS, clsSum, clsCnt, smem, bb);
    } else if (bb < 192) {
        scale_pass<2048, 256, 16, 32, 1, 256, 2>(fn3, fo3, labels, ncls, 3,
            pZn, pZo, pS, clsSum, clsCnt, smem, bb - 128);
    } else if (bb < 704) {
        scale_pass<512, 4096, 64, 8, 1, 128, 1>(fn1, fo1, labels, ncls, 1,
            pZn, pZo, pS, clsSum, clsCnt, smem, bb - 192);
    } else {
        scale_pass<256, 16384, 128, 4, 2, 128, 1>(fn0, fo0, labels, ncls, 0,
            pZn, pZo, pS, clsSum, clsCnt, smem, bb - 704);
    }
}

// scale-3 finish: combine channel-split partials into class bins
__global__ __launch_bounds__(TPB)
void k2_scale3(const int* __restrict__ labels,
               const float* __restrict__ pZn, const float* __restrict__ pZo,
               const float* __restrict__ pS,
               float* __restrict__ clsSum, float* __restrict__ clsCnt,
               const int* __restrict__ pNC) {
    const int ncls = *pNC;
    const int t = threadIdx.x;
    const int q = blockIdx.x * TPB + t;     // [0, 2048)
    __shared__ float ls[32], lc[32];
    if (t < 32) { ls[t] = 0.f; lc[t] = 0.f; }
    __syncthreads();
    const float zn = pZn[q];
    const float zo = pZo[q];
    const float s  = pS[q];
    const float kl = s / zn - logf(zn) + logf(zo);
    const int b  = q / 256;
    const int pp = q % 256;
    const int h  = pp / 16;
    const int w  = pp % 16;
    const int lab = labels[b * 262144 + (h * 32) * 512 + (w * 32)];
    if ((unsigned)lab < (unsigned)ncls) {
        atomicAdd(&ls[lab], kl);
        atomicAdd(&lc[lab], 1.0f);
    }
    __syncthreads();
    if (t < 32 && lc[t] != 0.f) {
        atomicAdd(&clsSum[96 + t], ls[t]);
        atomicAdd(&clsCnt[96 + t], lc[t]);
    }
}

__global__ void k3_finalize(const float* __restrict__ clsSum,
                            const float* __restrict__ clsCnt,
                            const int* __restrict__ pNC,
                            const int* __restrict__ pNOC,
                            float* __restrict__ out) {
    const int t = threadIdx.x;              // 64 threads, one wave
    const int ncls = *pNC;
    const int nold = *pNOC;
    float acc = 0.f;
    for (int i = t; i < 128; i += 64) {
        const int s_ = i / 32;
        const int c  = i % 32;
        if (c < ncls) {
            const float cnt = clsCnt[i];
            const float sum = clsSum[i];
            const float mean = (cnt > 0.f) ? (sum / cnt) : 0.f;
            const float coef = (c == 0) ? (float)nold / (float)ncls
                                        : ((c <= nold) ? 1.f : 0.f);
            acc += (float)(s_ + 1) * coef * mean;   // WEIGHTS = 1,2,3,4
        }
    }
    #pragma unroll
    for (int off = 32; off > 0; off >>= 1) acc += __shfl_down(acc, off, 64);
    if (t == 0) out[0] = acc;
}

extern "C" void kernel_launch(void* const* d_in, const int* in_sizes, int n_in,
                              void* d_out, int out_size, void* d_ws, size_t ws_size,
                              hipStream_t stream) {
    const int* labels = (const int*)d_in[0];
    const float* fn[4];
    const float* fo[4];

    if (in_sizes[2] == in_sizes[1]) {       // interleaved (expected)
        fn[0] = (const float*)d_in[1]; fo[0] = (const float*)d_in[2];
        fn[1] = (const float*)d_in[3]; fo[1] = (const float*)d_in[4];
        fn[2] = (const float*)d_in[5]; fo[2] = (const float*)d_in[6];
        fn[3] = (const float*)d_in[7]; fo[3] = (const float*)d_in[8];
    } else {                                 // grouped (reference signature)
        fn[0] = (const float*)d_in[1]; fn[1] = (const float*)d_in[2];
        fn[2] = (const float*)d_in[3]; fn[3] = (const float*)d_in[4];
        fo[0] = (const float*)d_in[5]; fo[1] = (const float*)d_in[6];
        fo[2] = (const float*)d_in[7]; fo[3] = (const float*)d_in[8];
    }
    const int* pNC  = (const int*)d_in[9];
    const int* pNOC = (const int*)d_in[10];

    float* ws = (float*)d_ws;
    float* pZn = ws;                 // 2048
    float* pZo = ws + P3;            // 2048
    float* pS  = ws + 2 * P3;        // 2048
    float* clsSum = ws + 3 * P3;     // 128
    float* clsCnt = clsSum + 128;    // 128

    k0_zero<<<(WS_ZERO_FLOATS + TPB - 1) / TPB, TPB, 0, stream>>>(ws);
    k1_fused<<<1728, TPB, 0, stream>>>(fn[0], fo[0], fn[1], fo[1],
                                       fn[2], fo[2], fn[3], fo[3],
                                       labels, pNC, pZn, pZo, pS, clsSum, clsCnt);
    k2_scale3<<<P3 / TPB, TPB, 0, stream>>>(labels, pZn, pZo, pS, clsSum, clsCnt, pNC);
    k3_finalize<<<1, 64, 0, stream>>>(clsSum, clsCnt, pNC, pNOC, (float*)d_out);
}